// Round 1
// baseline (3171.993 us; speedup 1.0000x reference)
//
#include <hip/hip_runtime.h>
#include <math.h>

#define B_ 1024
#define H_ 512
#define V_ 2048
#define T_ 32
#define G_ 2048   // 4*H

__device__ __forceinline__ float sigmoidf_(float x) {
    return 1.0f / (1.0f + expf(-x));
}

// C[M,N] = A[M,K] @ Bw[N,K]^T (+ bias[n] if addBias)
// 64x64 tile, 256 threads, 4x4 per thread, f32.
__global__ __launch_bounds__(256) void gemm_nt(const float* __restrict__ A,
                                               const float* __restrict__ Bw,
                                               float* __restrict__ C,
                                               const float* __restrict__ bias,
                                               int M, int N, int K, int addBias)
{
    __shared__ float As[16][68];   // +4 pad: keeps float4 alignment, breaks bank conflicts
    __shared__ float Bs[16][68];
    const int tid = threadIdx.x;
    const int bm = blockIdx.y * 64;
    const int bn = blockIdx.x * 64;
    const int tx = tid & 15;   // n-dim
    const int ty = tid >> 4;   // m-dim
    const int lk = tid & 15;   // k for staging
    const int lr = tid >> 4;   // row for staging
    float acc[4][4] = {};

    for (int kk = 0; kk < K; kk += 16) {
#pragma unroll
        for (int i = 0; i < 4; ++i) {
            As[lk][lr + 16 * i] = A[(size_t)(bm + lr + 16 * i) * K + kk + lk];
            Bs[lk][lr + 16 * i] = Bw[(size_t)(bn + lr + 16 * i) * K + kk + lk];
        }
        __syncthreads();
#pragma unroll
        for (int k = 0; k < 16; ++k) {
            float4 a4 = *(const float4*)&As[k][ty * 4];
            float4 b4 = *(const float4*)&Bs[k][tx * 4];
            float a[4] = {a4.x, a4.y, a4.z, a4.w};
            float b[4] = {b4.x, b4.y, b4.z, b4.w};
#pragma unroll
            for (int i = 0; i < 4; ++i)
#pragma unroll
                for (int j = 0; j < 4; ++j)
                    acc[i][j] += a[i] * b[j];
        }
        __syncthreads();
    }

#pragma unroll
    for (int i = 0; i < 4; ++i) {
        int m = bm + ty * 4 + i;
        int n = bn + tx * 4;
        float4 r;
        r.x = acc[i][0]; r.y = acc[i][1]; r.z = acc[i][2]; r.w = acc[i][3];
        if (addBias) {
            r.x += bias[n + 0]; r.y += bias[n + 1];
            r.z += bias[n + 2]; r.w += bias[n + 3];
        }
        *(float4*)&C[(size_t)m * N + n] = r;
    }
}

// h <- enc_h, c <- enc_c, mask <- 1, g0 <- 0
__global__ void init_state(const float* __restrict__ eh, const float* __restrict__ ec,
                           float* __restrict__ h, float* __restrict__ c,
                           float* __restrict__ mask, float* __restrict__ g0)
{
    int gid = blockIdx.x * 256 + threadIdx.x;
    if (gid < B_ * H_) { h[gid] = eh[gid]; c[gid] = ec[gid]; }
    if (gid < B_) mask[gid] = 1.0f;
    if (gid < G_) g0[gid] = 0.0f;
}

// W_ihT[v][j] = W_ih[j][v]   (both 2048x2048)
__global__ __launch_bounds__(256) void transpose2048(const float* __restrict__ in,
                                                     float* __restrict__ out)
{
    __shared__ float tile[32][33];
    int bx = blockIdx.x * 32;   // v
    int by = blockIdx.y * 32;   // j
    int tx = threadIdx.x & 31;
    int ty = threadIdx.x >> 5;  // 0..7
#pragma unroll
    for (int i = 0; i < 32; i += 8)
        tile[ty + i][tx] = in[(size_t)(by + ty + i) * V_ + bx + tx];
    __syncthreads();
#pragma unroll
    for (int i = 0; i < 32; i += 8)
        out[(size_t)(bx + ty + i) * G_ + by + tx] = tile[tx][ty + i];
}

// g0[j] = sum_v init_input[v] * W_ihT[v][j]   (init_input is zeros in practice)
__global__ void g0_kernel(const float* __restrict__ init_input,
                          const float* __restrict__ W_ihT,
                          float* __restrict__ g0)
{
    int j = blockIdx.x * 256 + threadIdx.x;   // gridDim.x = 8
    int v0 = blockIdx.y * 128;                // gridDim.y = 16
    float acc = 0.0f;
    for (int v = v0; v < v0 + 128; ++v)
        acc += init_input[v] * W_ihT[(size_t)v * G_ + j];
    atomicAdd(&g0[j], acc);
}

// gates = gates_hh + b_ih + b_hh + x_gates; LSTM cell update (in-place h, c)
__global__ __launch_bounds__(256) void lstm_update(const float* __restrict__ gates,
                                                   const float* __restrict__ b_ih,
                                                   const float* __restrict__ b_hh,
                                                   const float* __restrict__ W_ihT,
                                                   const float* __restrict__ g0,
                                                   const int* __restrict__ idx,
                                                   float* __restrict__ h,
                                                   float* __restrict__ c,
                                                   int t)
{
    int gid = blockIdx.x * 256 + threadIdx.x;  // B*H threads
    int b  = gid >> 9;          // /H_
    int jh = gid & (H_ - 1);
    const float* xrow;
    if (t == 0) {
        xrow = g0;
    } else {
        xrow = W_ihT + (size_t)idx[b] * G_;
    }
    const float* grow = gates + (size_t)b * G_;
    float gi = grow[jh]            + b_ih[jh]            + b_hh[jh]            + xrow[jh];
    float gf = grow[H_ + jh]       + b_ih[H_ + jh]       + b_hh[H_ + jh]       + xrow[H_ + jh];
    float gg = grow[2 * H_ + jh]   + b_ih[2 * H_ + jh]   + b_hh[2 * H_ + jh]   + xrow[2 * H_ + jh];
    float go = grow[3 * H_ + jh]   + b_ih[3 * H_ + jh]   + b_hh[3 * H_ + jh]   + xrow[3 * H_ + jh];
    float cn = sigmoidf_(gf) * c[gid] + sigmoidf_(gi) * tanhf(gg);
    c[gid] = cn;
    h[gid] = sigmoidf_(go) * tanhf(cn);
}

// Per-row argmax (first-index tie-break), one-hot scatter, mask bookkeeping.
__global__ __launch_bounds__(256) void argmax_step(const float* __restrict__ logits,
                                                   float* __restrict__ predicts,
                                                   float* __restrict__ masks_out,
                                                   float* __restrict__ mask,
                                                   int* __restrict__ idx,
                                                   const int* __restrict__ eos_idx)
{
    __shared__ float sval[256];
    __shared__ int   sidx[256];
    int b = blockIdx.x;
    const float* row = logits + (size_t)b * V_;
    float best = -INFINITY;
    int bi = V_;
    for (int v = threadIdx.x; v < V_; v += 256) {
        float x = row[v];
        if (x > best || (x == best && v < bi)) { best = x; bi = v; }
    }
    sval[threadIdx.x] = best;
    sidx[threadIdx.x] = bi;
    __syncthreads();
    for (int s = 128; s > 0; s >>= 1) {
        if (threadIdx.x < s) {
            float ov = sval[threadIdx.x + s];
            int   oi = sidx[threadIdx.x + s];
            if (ov > sval[threadIdx.x] ||
                (ov == sval[threadIdx.x] && oi < sidx[threadIdx.x])) {
                sval[threadIdx.x] = ov;
                sidx[threadIdx.x] = oi;
            }
        }
        __syncthreads();
    }
    if (threadIdx.x == 0) {
        int am = sidx[0];
        idx[b] = am;
        predicts[(size_t)b * V_ + am] = 1.0f;
        masks_out[b] = mask[b];
        if (am == *eos_idx) mask[b] = 0.0f;
    }
}

extern "C" void kernel_launch(void* const* d_in, const int* in_sizes, int n_in,
                              void* d_out, int out_size, void* d_ws, size_t ws_size,
                              hipStream_t stream) {
    const float* enc_h      = (const float*)d_in[0];
    const float* enc_c      = (const float*)d_in[1];
    const float* W_ih       = (const float*)d_in[2];
    const float* W_hh       = (const float*)d_in[3];
    const float* b_ih       = (const float*)d_in[4];
    const float* b_hh       = (const float*)d_in[5];
    const float* W_out      = (const float*)d_in[6];
    const float* b_out      = (const float*)d_in[7];
    const float* init_input = (const float*)d_in[8];
    // d_in[9] = max_len (fixed 32), d_in[10] = eos_idx
    const int* eos_idx = (const int*)d_in[10];

    float* out = (float*)d_out;
    float* predicts = out;                                // [T,B,V]
    float* logits   = out + (size_t)T_ * B_ * V_;         // [T,B,V]
    float* masks    = out + 2 * (size_t)T_ * B_ * V_;     // [T,1,B]

    // workspace layout
    char* wsp = (char*)d_ws;
    float* W_ihT = (float*)wsp;                 wsp += (size_t)V_ * G_ * 4;   // 16 MB
    float* gates = (float*)wsp;                 wsp += (size_t)B_ * G_ * 4;   // 8 MB
    float* h     = (float*)wsp;                 wsp += (size_t)B_ * H_ * 4;   // 2 MB
    float* c     = (float*)wsp;                 wsp += (size_t)B_ * H_ * 4;   // 2 MB
    float* g0    = (float*)wsp;                 wsp += (size_t)G_ * 4;
    float* mask  = (float*)wsp;                 wsp += (size_t)B_ * 4;
    int*   idx   = (int*)wsp;                   wsp += (size_t)B_ * 4;

    // predicts region must be zero (one-hot scatter fills the 1s)
    hipMemsetAsync(predicts, 0, (size_t)T_ * B_ * V_ * sizeof(float), stream);

    init_state<<<(B_ * H_ + 255) / 256, 256, 0, stream>>>(enc_h, enc_c, h, c, mask, g0);
    transpose2048<<<dim3(64, 64), 256, 0, stream>>>(W_ih, W_ihT);
    g0_kernel<<<dim3(8, 16), 256, 0, stream>>>(init_input, W_ihT, g0);

    for (int t = 0; t < T_; ++t) {
        // gates_hh = h @ W_hh^T   [1024,512] x [2048,512]^T
        gemm_nt<<<dim3(G_ / 64, B_ / 64), 256, 0, stream>>>(
            h, W_hh, gates, nullptr, B_, G_, H_, 0);
        // LSTM cell: h,c update (adds biases + W_ih column gather)
        lstm_update<<<(B_ * H_) / 256, 256, 0, stream>>>(
            gates, b_ih, b_hh, W_ihT, g0, idx, h, c, t);
        // logits[t] = h @ W_out^T + b_out
        gemm_nt<<<dim3(V_ / 64, B_ / 64), 256, 0, stream>>>(
            h, W_out, logits + (size_t)t * B_ * V_, b_out, B_, V_, H_, 1);
        // argmax + one-hot + mask
        argmax_step<<<B_, 256, 0, stream>>>(
            logits + (size_t)t * B_ * V_, predicts + (size_t)t * B_ * V_,
            masks + (size_t)t * B_, mask, idx, eos_idx);
    }
}

// Round 2
// 2403.671 us; speedup vs baseline: 1.3196x; 1.3196x over previous
//
#include <hip/hip_runtime.h>
#include <math.h>

#define B_ 1024
#define H_ 512
#define V_ 2048
#define T_ 32
#define G_ 2048   // 4*H
#define KP 1024   // packed plane width per row: hi[512] | lo[512]
#define K3 1536   // virtual K = 3*512 (hi*hi + hi*lo + lo*hi)

#define A_SCALE 64.0f
#define B_SCALE 256.0f
#define SCALE_INV (1.0f / (64.0f * 256.0f))

typedef _Float16 f16x8 __attribute__((ext_vector_type(8)));
typedef float f32x4 __attribute__((ext_vector_type(4)));

__device__ __forceinline__ float sigmoidf_(float x) {
    return 1.0f / (1.0f + expf(-x));
}

// 16-byte global -> LDS direct staging. Per-lane dst pointer; HW uses
// wave-uniform base (first lane) + lane*16, which matches our row-major layout.
__device__ __forceinline__ void stage16(const _Float16* g, _Float16* l) {
#if __has_builtin(__builtin_amdgcn_global_load_lds)
    __builtin_amdgcn_global_load_lds(
        (const __attribute__((address_space(1))) void*)g,
        (__attribute__((address_space(3))) void*)l, 16, 0, 0);
#else
    *(uint4*)l = *(const uint4*)g;
#endif
}

// ---------------------------------------------------------------------------
// GEMM1 fused: gates = h @ W_hh^T (fp16x2 MFMA, K3=1536) + biases + x-gather,
// then LSTM cell update in-register; writes c and split-packed h_new.
// Tile: 64 rows x 16 j (N=64 = 4 quadrants x 16). Grid (32, 16) = 512 WGs.
// Wave w owns rows [16w,16w+16) x all 4 quadrants -> i,f,g,o in-lane.
// ---------------------------------------------------------------------------
__global__ __launch_bounds__(256) void gemm1_fused(
    const _Float16* __restrict__ Hin,   // [B_][KP] packed h (scaled x64)
    const _Float16* __restrict__ Wg,    // [G_][KP] packed W_hh (scaled x256)
    const float* __restrict__ bsum,     // [G_] b_ih + b_hh
    const float* __restrict__ g0,       // [G_] init_input @ W_ih^T
    const float* __restrict__ W_ihT,    // [V_][G_] f32 (mode A)
    const float* __restrict__ W_ih,     // [G_][V_] f32 (mode B fallback)
    const int* __restrict__ idx,        // [B_] prev argmax
    float* __restrict__ c,              // [B_][H_] cell state (in/out)
    _Float16* __restrict__ Hout,        // [B_][KP] packed h_new
    int t, int modeA)
{
    __shared__ _Float16 As[64 * 32];
    __shared__ _Float16 Bs[64 * 32];
    const int tid = threadIdx.x;
    const int bm  = blockIdx.y * 64;
    const int bnj = blockIdx.x * 16;

    const int r   = tid >> 2;
    const int c16 = tid & 3;
    const int gcB = ((r >> 4) << 9) + bnj + (r & 15);   // quadrant-mapped W row
    const _Float16* aSrc = Hin + (size_t)(bm + r) * KP + c16 * 8;
    const _Float16* bSrc = Wg  + (size_t)gcB * KP + c16 * 8;
    _Float16* aDst = As + tid * 8;
    _Float16* bDst = Bs + tid * 8;

    const int w    = tid >> 6;
    const int lane = tid & 63;
    const int l15  = lane & 15;
    const int kq   = lane >> 4;

    f32x4 acc[4];
#pragma unroll
    for (int q = 0; q < 4; ++q) acc[q] = (f32x4){0.f, 0.f, 0.f, 0.f};

    for (int kk = 0; kk < K3; kk += 32) {
        const int aoff = (kk < 512) ? kk : kk - 512;    // [hi, hi, lo]
        const int boff = (kk < 1024) ? kk : kk - 1024;  // [hi, lo, hi]
        stage16(aSrc + aoff, aDst);
        stage16(bSrc + boff, bDst);
        asm volatile("s_waitcnt vmcnt(0)" ::: "memory");
        __syncthreads();
        f16x8 a = *(const f16x8*)&As[(w * 16 + l15) * 32 + kq * 8];
#pragma unroll
        for (int nt = 0; nt < 4; ++nt) {
            f16x8 b = *(const f16x8*)&Bs[(nt * 16 + l15) * 32 + kq * 8];
            acc[nt] = __builtin_amdgcn_mfma_f32_16x16x32_f16(a, b, acc[nt], 0, 0, 0);
        }
        __syncthreads();
    }

    // epilogue: lane owns j = bnj + l15, rows (w*16 + kq*4 + rg), all 4 gates
    const int j = bnj + l15;
#pragma unroll
    for (int rg = 0; rg < 4; ++rg) {
        const int row = bm + w * 16 + kq * 4 + rg;
        float xg0, xg1, xg2, xg3;
        if (t == 0) {
            xg0 = g0[j]; xg1 = g0[512 + j]; xg2 = g0[1024 + j]; xg3 = g0[1536 + j];
        } else if (modeA) {
            const float* xr = W_ihT + (size_t)idx[row] * G_;
            xg0 = xr[j]; xg1 = xr[512 + j]; xg2 = xr[1024 + j]; xg3 = xr[1536 + j];
        } else {
            const int v = idx[row];
            xg0 = W_ih[(size_t)(j) * V_ + v];
            xg1 = W_ih[(size_t)(512 + j) * V_ + v];
            xg2 = W_ih[(size_t)(1024 + j) * V_ + v];
            xg3 = W_ih[(size_t)(1536 + j) * V_ + v];
        }
        const float gi = acc[0][rg] * SCALE_INV + bsum[j]        + xg0;
        const float gf = acc[1][rg] * SCALE_INV + bsum[512 + j]  + xg1;
        const float gg = acc[2][rg] * SCALE_INV + bsum[1024 + j] + xg2;
        const float go = acc[3][rg] * SCALE_INV + bsum[1536 + j] + xg3;
        const float co = c[(size_t)row * H_ + j];
        const float cn = sigmoidf_(gf) * co + sigmoidf_(gi) * tanhf(gg);
        const float hn = sigmoidf_(go) * tanhf(cn);
        c[(size_t)row * H_ + j] = cn;
        const float hs = A_SCALE * hn;
        const _Float16 hi = (_Float16)hs;
        const _Float16 lo = (_Float16)(hs - (float)hi);
        Hout[(size_t)row * KP + j] = hi;
        Hout[(size_t)row * KP + 512 + j] = lo;
    }
}

// ---------------------------------------------------------------------------
// GEMM2 fused: logits = h_new @ W_out^T + b_out (fp16x2 MFMA), plus per-32-col
// argmax partials (val+idx, first-index tie-break) written to ws.
// Tile 64x64, waves 2x2 (32x32 each). Grid (32, 16) = 512 WGs.
// ---------------------------------------------------------------------------
__global__ __launch_bounds__(256) void gemm2_fused(
    const _Float16* __restrict__ Hin,   // [B_][KP]
    const _Float16* __restrict__ Wo,    // [V_][KP]
    const float* __restrict__ b_out,    // [V_]
    float* __restrict__ logits,         // [B_][V_]
    float* __restrict__ pval,           // [B_][64]
    int* __restrict__ pidx)             // [B_][64]
{
    __shared__ _Float16 As[64 * 32];
    __shared__ _Float16 Bs[64 * 32];
    const int tid = threadIdx.x;
    const int bm = blockIdx.y * 64;
    const int bn = blockIdx.x * 64;

    const int r   = tid >> 2;
    const int c16 = tid & 3;
    const _Float16* aSrc = Hin + (size_t)(bm + r) * KP + c16 * 8;
    const _Float16* bSrc = Wo  + (size_t)(bn + r) * KP + c16 * 8;
    _Float16* aDst = As + tid * 8;
    _Float16* bDst = Bs + tid * 8;

    const int w    = tid >> 6;
    const int wm   = w & 1;
    const int wn   = w >> 1;
    const int lane = tid & 63;
    const int l15  = lane & 15;
    const int kq   = lane >> 4;

    f32x4 acc[2][2];
#pragma unroll
    for (int i = 0; i < 2; ++i)
#pragma unroll
        for (int k = 0; k < 2; ++k) acc[i][k] = (f32x4){0.f, 0.f, 0.f, 0.f};

    for (int kk = 0; kk < K3; kk += 32) {
        const int aoff = (kk < 512) ? kk : kk - 512;
        const int boff = (kk < 1024) ? kk : kk - 1024;
        stage16(aSrc + aoff, aDst);
        stage16(bSrc + boff, bDst);
        asm volatile("s_waitcnt vmcnt(0)" ::: "memory");
        __syncthreads();
        f16x8 a0 = *(const f16x8*)&As[(wm * 32 + l15) * 32 + kq * 8];
        f16x8 a1 = *(const f16x8*)&As[(wm * 32 + 16 + l15) * 32 + kq * 8];
        f16x8 b0 = *(const f16x8*)&Bs[(wn * 32 + l15) * 32 + kq * 8];
        f16x8 b1 = *(const f16x8*)&Bs[(wn * 32 + 16 + l15) * 32 + kq * 8];
        acc[0][0] = __builtin_amdgcn_mfma_f32_16x16x32_f16(a0, b0, acc[0][0], 0, 0, 0);
        acc[0][1] = __builtin_amdgcn_mfma_f32_16x16x32_f16(a0, b1, acc[0][1], 0, 0, 0);
        acc[1][0] = __builtin_amdgcn_mfma_f32_16x16x32_f16(a1, b0, acc[1][0], 0, 0, 0);
        acc[1][1] = __builtin_amdgcn_mfma_f32_16x16x32_f16(a1, b1, acc[1][1], 0, 0, 0);
        __syncthreads();
    }

    const int cid = blockIdx.x * 2 + wn;      // 32-col chunk id, 0..63
    const int c0  = bn + wn * 32 + l15;
    const int c1  = c0 + 16;
    const float bo0 = b_out[c0];
    const float bo1 = b_out[c1];
#pragma unroll
    for (int mt = 0; mt < 2; ++mt) {
#pragma unroll
        for (int rg = 0; rg < 4; ++rg) {
            const int row = bm + wm * 32 + mt * 16 + kq * 4 + rg;
            const float v0 = acc[mt][0][rg] * SCALE_INV + bo0;
            const float v1 = acc[mt][1][rg] * SCALE_INV + bo1;
            logits[(size_t)row * V_ + c0] = v0;
            logits[(size_t)row * V_ + c1] = v1;
            float bv; int bc;
            if (v1 > v0) { bv = v1; bc = c1; } else { bv = v0; bc = c0; }
#pragma unroll
            for (int off = 1; off < 16; off <<= 1) {
                const float ov = __shfl_xor(bv, off, 64);
                const int   oc = __shfl_xor(bc, off, 64);
                if (ov > bv || (ov == bv && oc < bc)) { bv = ov; bc = oc; }
            }
            if (l15 == 0) { pval[row * 64 + cid] = bv; pidx[row * 64 + cid] = bc; }
        }
    }
}

// Reduce 64 partials/row (ascending chunk order keeps first-index tie-break),
// scatter one-hot, mask bookkeeping.
__global__ __launch_bounds__(256) void finalize_step(
    const float* __restrict__ pval, const int* __restrict__ pidx,
    float* __restrict__ predicts_t, float* __restrict__ masks_t,
    float* __restrict__ mask, int* __restrict__ idx,
    const int* __restrict__ eos_idx)
{
    const int row = blockIdx.x * 256 + threadIdx.x;   // grid 4
    if (row >= B_) return;
    float bv = pval[row * 64];
    int   bc = pidx[row * 64];
    for (int cd = 1; cd < 64; ++cd) {
        const float v = pval[row * 64 + cd];
        if (v > bv) { bv = v; bc = pidx[row * 64 + cd]; }
    }
    idx[row] = bc;
    predicts_t[(size_t)row * V_ + bc] = 1.0f;
    masks_t[row] = mask[row];
    if (bc == *eos_idx) mask[row] = 0.0f;
}

// h/c init + split-pack of encoder_hidden, bsum, mask=1
__global__ __launch_bounds__(256) void prep_misc(
    const float* __restrict__ eh, const float* __restrict__ ec,
    const float* __restrict__ b_ih, const float* __restrict__ b_hh,
    _Float16* __restrict__ hA, float* __restrict__ c,
    float* __restrict__ bsum, float* __restrict__ mask)
{
    const int gid = blockIdx.x * 256 + threadIdx.x;   // grid 2048 -> B_*H_
    const int row = gid >> 9;
    const int j   = gid & 511;
    const float x = eh[gid];
    c[gid] = ec[gid];
    const float xs = A_SCALE * x;
    const _Float16 hi = (_Float16)xs;
    const _Float16 lo = (_Float16)(xs - (float)hi);
    hA[(size_t)row * KP + j] = hi;
    hA[(size_t)row * KP + 512 + j] = lo;
    if (gid < G_) bsum[gid] = b_ih[gid] + b_hh[gid];
    if (gid < B_) mask[gid] = 1.0f;
}

// split-pack W_hh and W_out (x256) into [n][hi(512)|lo(512)] fp16 planes
__global__ __launch_bounds__(256) void prep_w(
    const float* __restrict__ W_hh, const float* __restrict__ W_out,
    _Float16* __restrict__ Wg, _Float16* __restrict__ Wo)
{
    const int gid = blockIdx.x * 256 + threadIdx.x;   // grid 8192 -> 2*G_*H_
    const int sel = gid >> 20;
    const int i   = gid & 1048575;
    const int n   = i >> 9;
    const int k   = i & 511;
    const float ws = (sel ? W_out[i] : W_hh[i]) * B_SCALE;
    const _Float16 hi = (_Float16)ws;
    const _Float16 lo = (_Float16)(ws - (float)hi);
    _Float16* dst = sel ? Wo : Wg;
    dst[(size_t)n * KP + k] = hi;
    dst[(size_t)n * KP + 512 + k] = lo;
}

// W_ihT[v][gc] = W_ih[gc][v], f32 (mode A only)
__global__ __launch_bounds__(256) void transpose2048(const float* __restrict__ in,
                                                     float* __restrict__ out)
{
    __shared__ float tile[32][33];
    const int bx = blockIdx.x * 32;   // v
    const int by = blockIdx.y * 32;   // gc
    const int tx = threadIdx.x & 31;
    const int ty = threadIdx.x >> 5;  // 0..7
#pragma unroll
    for (int i = 0; i < 32; i += 8)
        tile[ty + i][tx] = in[(size_t)(by + ty + i) * V_ + bx + tx];
    __syncthreads();
#pragma unroll
    for (int i = 0; i < 32; i += 8)
        out[(size_t)(bx + ty + i) * G_ + by + tx] = tile[tx][ty + i];
}

// g0[gc] = dot(init_input, W_ih[gc]), one wave per gc
__global__ __launch_bounds__(256) void g0_kernel(const float* __restrict__ init_input,
                                                 const float* __restrict__ W_ih,
                                                 float* __restrict__ g0)
{
    const int gc   = blockIdx.x * 4 + (threadIdx.x >> 6);  // grid 512
    const int lane = threadIdx.x & 63;
    float acc = 0.0f;
    for (int v = lane; v < V_; v += 64) acc += init_input[v] * W_ih[(size_t)gc * V_ + v];
#pragma unroll
    for (int off = 32; off > 0; off >>= 1) acc += __shfl_down(acc, off, 64);
    if (lane == 0) g0[gc] = acc;
}

extern "C" void kernel_launch(void* const* d_in, const int* in_sizes, int n_in,
                              void* d_out, int out_size, void* d_ws, size_t ws_size,
                              hipStream_t stream) {
    const float* enc_h      = (const float*)d_in[0];
    const float* enc_c      = (const float*)d_in[1];
    const float* W_ih       = (const float*)d_in[2];
    const float* W_hh       = (const float*)d_in[3];
    const float* b_ih       = (const float*)d_in[4];
    const float* b_hh       = (const float*)d_in[5];
    const float* W_out      = (const float*)d_in[6];
    const float* b_out      = (const float*)d_in[7];
    const float* init_input = (const float*)d_in[8];
    const int*   eos_idx    = (const int*)d_in[10];

    float* out      = (float*)d_out;
    float* predicts = out;
    float* logits   = out + (size_t)T_ * B_ * V_;
    float* masks    = out + 2 * (size_t)T_ * B_ * V_;

    size_t off = 0;
    auto alloc = [&](size_t bytes) {
        void* p = (char*)d_ws + off;
        off += (bytes + 255) & ~(size_t)255;
        return p;
    };
    _Float16* Wg   = (_Float16*)alloc((size_t)G_ * KP * 2);
    _Float16* Wo   = (_Float16*)alloc((size_t)V_ * KP * 2);
    _Float16* hA   = (_Float16*)alloc((size_t)B_ * KP * 2);
    _Float16* hB   = (_Float16*)alloc((size_t)B_ * KP * 2);
    float*    c    = (float*)alloc((size_t)B_ * H_ * 4);
    float*    pval = (float*)alloc((size_t)B_ * 64 * 4);
    int*      pidx = (int*)alloc((size_t)B_ * 64 * 4);
    float*    g0   = (float*)alloc((size_t)G_ * 4);
    float*    bsum = (float*)alloc((size_t)G_ * 4);
    float*    mask = (float*)alloc((size_t)B_ * 4);
    int*      idx  = (int*)alloc((size_t)B_ * 4);
    float*    W_ihT = (float*)((char*)d_ws + off);
    const int modeA = (off + (size_t)V_ * G_ * 4) <= ws_size;   // coalesced gather path

    hipMemsetAsync(predicts, 0, (size_t)T_ * B_ * V_ * sizeof(float), stream);
    prep_misc<<<(B_ * H_) / 256, 256, 0, stream>>>(enc_h, enc_c, b_ih, b_hh, hA, c, bsum, mask);
    prep_w<<<(2 * G_ * H_) / 256, 256, 0, stream>>>(W_hh, W_out, Wg, Wo);
    g0_kernel<<<G_ / 4, 256, 0, stream>>>(init_input, W_ih, g0);
    if (modeA)
        transpose2048<<<dim3(64, 64), 256, 0, stream>>>(W_ih, W_ihT);

    for (int t = 0; t < T_; ++t) {
        const _Float16* hin = (t & 1) ? hB : hA;
        _Float16*      hout = (t & 1) ? hA : hB;
        gemm1_fused<<<dim3(32, 16), 256, 0, stream>>>(
            hin, Wg, bsum, g0, W_ihT, W_ih, idx, c, hout, t, modeA);
        gemm2_fused<<<dim3(32, 16), 256, 0, stream>>>(
            hout, Wo, b_out, logits + (size_t)t * B_ * V_, pval, pidx);
        finalize_step<<<4, 256, 0, stream>>>(
            pval, pidx, predicts + (size_t)t * B_ * V_, masks + (size_t)t * B_,
            mask, idx, eos_idx);
    }
}